// Round 1
// baseline (624.343 us; speedup 1.0000x reference)
//
#include <hip/hip_runtime.h>
#include <cstdint>
#include <cstddef>

#define H 128

typedef __bf16 v8bf __attribute__((ext_vector_type(8)));
typedef float v4f __attribute__((ext_vector_type(4)));

struct MatDesc {
    const __bf16* A;   // [Mpad,128] bf16
    const float*  W;   // [128,128] f32 (row-major; we compute A @ W^T)
    const float*  bias; // [128] or nullptr
    __bf16*       C;   // [Mpad,128] bf16 out
};
struct MatBatch { MatDesc m[7]; };

// ---------------- convert fp32 -> bf16 (x_emb, child_h) + zero counts ----------------
__global__ __launch_bounds__(256) void convert_k(const float* __restrict__ x,
                                                 const float* __restrict__ chh,
                                                 __bf16* __restrict__ xe,
                                                 __bf16* __restrict__ che,
                                                 int MH, int* __restrict__ counts, int M) {
    int i = blockIdx.x * 256 + threadIdx.x;
    if (i < MH) {
        xe[i]  = (__bf16)x[i];
        che[i] = (__bf16)chh[i];
    }
    if (i < M) counts[i] = 0;
}

// ---------------- batched GEMM: C = A @ W^T (+bias), bf16 MFMA ----------------
// block = 256 threads = 4 waves; each wave does 16 rows x 128 cols; block = 64 rows.
__global__ __launch_bounds__(256) void gemm_batch(MatBatch batch, int M) {
    const MatDesc d = batch.m[blockIdx.y];
    __shared__ __bf16 wlds[H][H + 8];   // pad: row stride 136 elems = 272B (16B-aligned, 2-way bank alias only)

    for (int i = threadIdx.x; i < H * H; i += 256)
        wlds[i >> 7][i & 127] = (__bf16)d.W[i];
    __syncthreads();

    const int wave = threadIdx.x >> 6;
    const int lane = threadIdx.x & 63;
    const int quad = lane >> 4;
    const int l16  = lane & 15;
    const int r0   = blockIdx.x * 64 + wave * 16;

    v4f acc[8];
#pragma unroll
    for (int nt = 0; nt < 8; ++nt) acc[nt] = (v4f){0.f, 0.f, 0.f, 0.f};

    const __bf16* arow = d.A + (size_t)(r0 + l16) * H + quad * 8;
#pragma unroll
    for (int k0 = 0; k0 < H; k0 += 32) {
        v8bf a = *(const v8bf*)(arow + k0);
#pragma unroll
        for (int nt = 0; nt < 8; ++nt) {
            v8bf b = *(const v8bf*)(&wlds[nt * 16 + l16][k0 + quad * 8]);
            acc[nt] = __builtin_amdgcn_mfma_f32_16x16x32_bf16(a, b, acc[nt], 0, 0, 0);
        }
    }

#pragma unroll
    for (int nt = 0; nt < 8; ++nt) {
        int n = nt * 16 + l16;
        float bia = d.bias ? d.bias[n] : 0.f;
#pragma unroll
        for (int r = 0; r < 4; ++r) {
            int m = r0 + quad * 4 + r;
            if (m < M) d.C[(size_t)m * H + n] = (__bf16)(acc[nt][r] + bia);
        }
    }
}

// ---------------- edge pass: e = tanh(Ah[chi]+Bx[ci]) . v ; expe = exp(e); histogram ----------------
__global__ __launch_bounds__(256) void edge_e(const __bf16* __restrict__ Ah,
                                              const __bf16* __restrict__ Bx,
                                              const int* __restrict__ ci,
                                              const int* __restrict__ chi,
                                              const float* __restrict__ vw,
                                              float* __restrict__ expe,
                                              int* __restrict__ counts, int L) {
    int l = blockIdx.x * 4 + (threadIdx.x >> 6);
    int lane = threadIdx.x & 63;
    if (l >= L) return;
    int c = ci[l], ch = chi[l];
    const __bf16* ar = Ah + (size_t)ch * H + lane * 2;
    const __bf16* br = Bx + (size_t)c * H + lane * 2;
    float v0 = vw[lane * 2], v1 = vw[lane * 2 + 1];
    float s = tanhf((float)ar[0] + (float)br[0]) * v0
            + tanhf((float)ar[1] + (float)br[1]) * v1;
#pragma unroll
    for (int off = 32; off > 0; off >>= 1) s += __shfl_xor(s, off);
    if (lane == 0) {
        expe[l] = __expf(s);
        atomicAdd(&counts[c], 1);
    }
}

// ---------------- exclusive scan over counts -> rowptr, cursor (single block) ----------------
__global__ __launch_bounds__(1024) void scan_k(const int* __restrict__ counts,
                                               int* __restrict__ rowptr,
                                               int* __restrict__ cursor, int M) {
    __shared__ int s[1024];
    __shared__ int carry;
    int tid = threadIdx.x;
    if (tid == 0) carry = 0;
    __syncthreads();
    for (int base = 0; base < M; base += 1024) {
        int idx = base + tid;
        int v = (idx < M) ? counts[idx] : 0;
        s[tid] = v;
        __syncthreads();
        for (int off = 1; off < 1024; off <<= 1) {
            int t = (tid >= off) ? s[tid - off] : 0;
            __syncthreads();
            s[tid] += t;
            __syncthreads();
        }
        int cbase = carry;
        if (idx < M) {
            int excl = cbase + s[tid] - v;
            rowptr[idx] = excl;
            cursor[idx] = excl;
        }
        __syncthreads();
        if (tid == 0) carry = cbase + s[1023];
        __syncthreads();
    }
    if (tid == 0) rowptr[M] = carry;
}

// ---------------- scatter edges into CSR ----------------
__global__ __launch_bounds__(256) void scatter_k(const int* __restrict__ ci,
                                                 int* __restrict__ cursor,
                                                 int* __restrict__ edge_list, int L) {
    int l = blockIdx.x * 256 + threadIdx.x;
    if (l < L) {
        int pos = atomicAdd(&cursor[ci[l]], 1);
        edge_list[pos] = l;
    }
}

// ---------------- per-segment: softmax weights, h_hat, sum_f_c ----------------
__global__ __launch_bounds__(128) void segment_k(const int* __restrict__ rowptr,
                                                 const int* __restrict__ edge_list,
                                                 const int* __restrict__ chi,
                                                 const float* __restrict__ expe,
                                                 const __bf16* __restrict__ Wfx,
                                                 const __bf16* __restrict__ Ufh,
                                                 const __bf16* __restrict__ ch16,
                                                 const float* __restrict__ child_c,
                                                 __bf16* __restrict__ hhat,
                                                 float* __restrict__ sumfc, int M) {
    int m = blockIdx.x;
    int h = threadIdx.x;
    int start = rowptr[m], end = rowptr[m + 1];
    int deg = end - start;
    __shared__ float red[128];
    float part = 0.f;
    for (int j = h; j < deg; j += 128) part += expe[edge_list[start + j]];
    red[h] = part;
    __syncthreads();
#pragma unroll
    for (int s = 64; s > 0; s >>= 1) {
        if (h < s) red[h] += red[h + s];
        __syncthreads();
    }
    float inv = 1.f / (red[0] + 1e-9f);
    float wfx = (float)Wfx[(size_t)m * H + h];
    float acch = 0.f, accf = 0.f;
    for (int j = 0; j < deg; ++j) {
        int l = edge_list[start + j];
        int ch = chi[l];
        float a = expe[l] * inv;
        size_t rb = (size_t)ch * H + h;
        acch += a * (float)ch16[rb];
        float f = 1.f / (1.f + __expf(-(wfx + (float)Ufh[rb])));
        accf += f * child_c[rb];
    }
    hhat[(size_t)m * H + h] = (__bf16)acch;
    sumfc[(size_t)m * H + h] = accf;
}

// ---------------- epilogue: gates -> h, c ----------------
__global__ __launch_bounds__(256) void final_k(const __bf16* __restrict__ Xi, const __bf16* __restrict__ Hi,
                                               const __bf16* __restrict__ Xc, const __bf16* __restrict__ Hc,
                                               const __bf16* __restrict__ Xo, const __bf16* __restrict__ Ho,
                                               const float* __restrict__ sumfc,
                                               float* __restrict__ out, int MH) {
    int i = blockIdx.x * 256 + threadIdx.x;
    if (i >= MH) return;
    float ig = 1.f / (1.f + __expf(-((float)Xi[i] + (float)Hi[i])));
    float ct = tanhf((float)Xc[i] + (float)Hc[i]);
    float og = 1.f / (1.f + __expf(-((float)Xo[i] + (float)Ho[i])));
    float c = ig * ct + sumfc[i];
    out[i] = og * tanhf(c);
    out[MH + i] = c;
}

extern "C" void kernel_launch(void* const* d_in, const int* in_sizes, int n_in,
                              void* d_out, int out_size, void* d_ws, size_t ws_size,
                              hipStream_t stream) {
    const float* x_emb   = (const float*)d_in[0];
    const float* child_h = (const float*)d_in[1];
    const float* child_c = (const float*)d_in[2];
    const int*   ci      = (const int*)d_in[3];
    const int*   chi     = (const int*)d_in[4];
    const float* Wi_w = (const float*)d_in[5];
    const float* Ui_w = (const float*)d_in[6];
    const float* Wf_w = (const float*)d_in[7];
    const float* Uf_w = (const float*)d_in[8];
    const float* Wo_w = (const float*)d_in[9];
    const float* Uo_w = (const float*)d_in[10];
    const float* Wc_w = (const float*)d_in[11];
    const float* Uc_w = (const float*)d_in[12];
    const float* Wa_w = (const float*)d_in[13];
    const float* Ua_w = (const float*)d_in[14];
    const float* Wi_b = (const float*)d_in[15];
    const float* Wf_b = (const float*)d_in[16];
    const float* Wo_b = (const float*)d_in[17];
    const float* Wc_b = (const float*)d_in[18];
    const float* Wa_b = (const float*)d_in[19];
    const float* vw   = (const float*)d_in[20];

    const int M    = in_sizes[0] / H;
    const int L    = in_sizes[3];
    const int Mpad = (M + 63) & ~63;
    const int MH   = M * H;

    char* p = (char*)d_ws;
    auto alloc = [&](size_t bytes) {
        char* r = p;
        p += (bytes + 255) & ~(size_t)255;
        return (void*)r;
    };
    size_t bfbytes = (size_t)Mpad * H * sizeof(__bf16);
    __bf16* xe16   = (__bf16*)alloc(bfbytes);
    __bf16* ch16   = (__bf16*)alloc(bfbytes);
    __bf16* hhat16 = (__bf16*)alloc(bfbytes);
    __bf16* Ah16   = (__bf16*)alloc(bfbytes);
    __bf16* Bx16   = (__bf16*)alloc(bfbytes);
    __bf16* Wfx16  = (__bf16*)alloc(bfbytes);
    __bf16* Ufh16  = (__bf16*)alloc(bfbytes);
    __bf16* Xi16   = (__bf16*)alloc(bfbytes);
    __bf16* Xc16   = (__bf16*)alloc(bfbytes);
    __bf16* Xo16   = (__bf16*)alloc(bfbytes);
    float* sumfc     = (float*)alloc((size_t)MH * 4);
    float* expe      = (float*)alloc((size_t)L * 4);
    int*   edge_list = (int*)alloc((size_t)L * 4);
    int*   counts    = (int*)alloc((size_t)M * 4);
    int*   rowptr    = (int*)alloc((size_t)(M + 1) * 4);
    int*   cursor    = (int*)alloc((size_t)M * 4);
    // buffer reuse: Ah/Bx dead after edge pass, Wfx dead after segment pass
    __bf16* Hi16 = Ah16;
    __bf16* Hc16 = Bx16;
    __bf16* Ho16 = Wfx16;

    convert_k<<<(MH + 255) / 256, 256, 0, stream>>>(x_emb, child_h, xe16, ch16, MH, counts, M);

    MatBatch ba{};
    ba.m[0] = MatDesc{ch16, Wa_w, Wa_b, Ah16};
    ba.m[1] = MatDesc{xe16, Ua_w, nullptr, Bx16};
    ba.m[2] = MatDesc{xe16, Wf_w, Wf_b, Wfx16};
    ba.m[3] = MatDesc{ch16, Uf_w, nullptr, Ufh16};
    ba.m[4] = MatDesc{xe16, Wi_w, Wi_b, Xi16};
    ba.m[5] = MatDesc{xe16, Wc_w, Wc_b, Xc16};
    ba.m[6] = MatDesc{xe16, Wo_w, Wo_b, Xo16};
    dim3 gA(Mpad / 64, 7);
    gemm_batch<<<gA, 256, 0, stream>>>(ba, M);

    edge_e<<<(L + 3) / 4, 256, 0, stream>>>(Ah16, Bx16, ci, chi, vw, expe, counts, L);
    scan_k<<<1, 1024, 0, stream>>>(counts, rowptr, cursor, M);
    scatter_k<<<(L + 255) / 256, 256, 0, stream>>>(ci, cursor, edge_list, L);
    segment_k<<<M, 128, 0, stream>>>(rowptr, edge_list, chi, expe, Wfx16, Ufh16, ch16, child_c,
                                     hhat16, sumfc, M);

    MatBatch bb{};
    bb.m[0] = MatDesc{hhat16, Ui_w, nullptr, Hi16};
    bb.m[1] = MatDesc{hhat16, Uc_w, nullptr, Hc16};
    bb.m[2] = MatDesc{hhat16, Uo_w, nullptr, Ho16};
    dim3 gB(Mpad / 64, 3);
    gemm_batch<<<gB, 256, 0, stream>>>(bb, M);

    final_k<<<(MH + 255) / 256, 256, 0, stream>>>(Xi16, Hi16, Xc16, Hc16, Xo16, Ho16, sumfc,
                                                  (float*)d_out, MH);
}

// Round 2
// 435.142 us; speedup vs baseline: 1.4348x; 1.4348x over previous
//
#include <hip/hip_runtime.h>
#include <cstdint>
#include <cstddef>

#define H 128

typedef __bf16 v8bf __attribute__((ext_vector_type(8)));
typedef __bf16 v4bf __attribute__((ext_vector_type(4)));
typedef float  v4f  __attribute__((ext_vector_type(4)));

__device__ __forceinline__ float ftanh(float x) {
    return 1.f - 2.f / (1.f + __expf(2.f * x));
}
__device__ __forceinline__ float fsigm(float x) {
    return 1.f / (1.f + __expf(-x));
}

struct MatDesc {
    const __bf16* A;    // [Mpad,128] bf16
    const float*  W;    // [128,128] f32 (row-major; compute A @ W^T)
    const float*  bias; // [128] or nullptr
    __bf16*       C;    // [Mpad,128] bf16 out
};
struct MatBatch { MatDesc m[7]; };

// ---------------- convert fp32 -> bf16 (x_emb, child_h), vectorized x4; zero counts ----------------
__global__ __launch_bounds__(256) void convert_k(const float* __restrict__ x,
                                                 const float* __restrict__ chh,
                                                 __bf16* __restrict__ xe,
                                                 __bf16* __restrict__ che,
                                                 int MH4, int* __restrict__ counts, int M) {
    int i = blockIdx.x * 256 + threadIdx.x;
    if (i < MH4) {
        v4f a = ((const v4f*)x)[i];
        v4f b = ((const v4f*)chh)[i];
        v4bf ab, bb;
#pragma unroll
        for (int k = 0; k < 4; ++k) { ab[k] = (__bf16)a[k]; bb[k] = (__bf16)b[k]; }
        ((v4bf*)xe)[i] = ab;
        ((v4bf*)che)[i] = bb;
    }
    if (i < M) counts[i] = 0;
}

// ---------------- batched GEMM: C = A @ W^T (+bias), bf16 MFMA ----------------
__global__ __launch_bounds__(256) void gemm_batch(MatBatch batch, int M) {
    const MatDesc d = batch.m[blockIdx.y];
    __shared__ __bf16 wlds[H][H + 8];

    for (int i = threadIdx.x; i < H * H; i += 256)
        wlds[i >> 7][i & 127] = (__bf16)d.W[i];
    __syncthreads();

    const int wave = threadIdx.x >> 6;
    const int lane = threadIdx.x & 63;
    const int quad = lane >> 4;
    const int l16  = lane & 15;
    const int r0   = blockIdx.x * 64 + wave * 16;

    v4f acc[8];
#pragma unroll
    for (int nt = 0; nt < 8; ++nt) acc[nt] = (v4f){0.f, 0.f, 0.f, 0.f};

    const __bf16* arow = d.A + (size_t)(r0 + l16) * H + quad * 8;
#pragma unroll
    for (int k0 = 0; k0 < H; k0 += 32) {
        v8bf a = *(const v8bf*)(arow + k0);
#pragma unroll
        for (int nt = 0; nt < 8; ++nt) {
            v8bf b = *(const v8bf*)(&wlds[nt * 16 + l16][k0 + quad * 8]);
            acc[nt] = __builtin_amdgcn_mfma_f32_16x16x32_bf16(a, b, acc[nt], 0, 0, 0);
        }
    }

#pragma unroll
    for (int nt = 0; nt < 8; ++nt) {
        int n = nt * 16 + l16;
        float bia = d.bias ? d.bias[n] : 0.f;
#pragma unroll
        for (int r = 0; r < 4; ++r) {
            int m = r0 + quad * 4 + r;
            if (m < M) d.C[(size_t)m * H + n] = (__bf16)(acc[nt][r] + bia);
        }
    }
}

// ---------------- edge pass: 16 lanes/edge, 8 feats/lane; fast tanh; histogram ----------------
__global__ __launch_bounds__(256) void edge_e(const __bf16* __restrict__ Ah,
                                              const __bf16* __restrict__ Bx,
                                              const int* __restrict__ ci,
                                              const int* __restrict__ chi,
                                              const float* __restrict__ vw,
                                              float* __restrict__ expe,
                                              int* __restrict__ counts, int L) {
    int tid = threadIdx.x;
    int sub = tid & 15;
    int l = blockIdx.x * 16 + (tid >> 4);
    if (l >= L) return;
    int c = ci[l], ch = chi[l];
    v8bf a = *(const v8bf*)(Ah + (size_t)ch * H + sub * 8);
    v8bf b = *(const v8bf*)(Bx + (size_t)c * H + sub * 8);
    v4f v0 = *(const v4f*)(vw + sub * 8);
    v4f v1 = *(const v4f*)(vw + sub * 8 + 4);
    float s = 0.f;
#pragma unroll
    for (int k = 0; k < 8; ++k) {
        float x = (float)a[k] + (float)b[k];
        float vv = (k < 4) ? v0[k] : v1[k - 4];
        s += ftanh(x) * vv;
    }
    s += __shfl_xor(s, 1);
    s += __shfl_xor(s, 2);
    s += __shfl_xor(s, 4);
    s += __shfl_xor(s, 8);
    if (sub == 0) {
        expe[l] = __expf(s);
        atomicAdd(&counts[c], 1);
    }
}

// ---------------- 3-kernel parallel scan ----------------
__global__ __launch_bounds__(1024) void scan_local(const int* __restrict__ counts,
                                                   int* __restrict__ excl,
                                                   int* __restrict__ bsums, int M) {
    __shared__ int s[1024];
    int tid = threadIdx.x;
    int idx = blockIdx.x * 1024 + tid;
    int v = (idx < M) ? counts[idx] : 0;
    s[tid] = v;
    __syncthreads();
    for (int off = 1; off < 1024; off <<= 1) {
        int t = (tid >= off) ? s[tid - off] : 0;
        __syncthreads();
        s[tid] += t;
        __syncthreads();
    }
    if (idx < M) excl[idx] = s[tid] - v;
    if (tid == 1023) bsums[blockIdx.x] = s[1023];
}

__global__ __launch_bounds__(1024) void scan_tops(const int* __restrict__ bsums,
                                                  int* __restrict__ boffs, int nb) {
    __shared__ int s[1024];
    int tid = threadIdx.x;
    int v = (tid < nb) ? bsums[tid] : 0;
    s[tid] = v;
    __syncthreads();
    for (int off = 1; off < 1024; off <<= 1) {
        int t = (tid >= off) ? s[tid - off] : 0;
        __syncthreads();
        s[tid] += t;
        __syncthreads();
    }
    if (tid < nb) boffs[tid] = s[tid] - v;
}

__global__ __launch_bounds__(1024) void scan_add(int* __restrict__ rowptr,
                                                 int* __restrict__ cursor,
                                                 const int* __restrict__ boffs,
                                                 const int* __restrict__ counts, int M) {
    int idx = blockIdx.x * 1024 + threadIdx.x;
    if (idx < M) {
        int v = rowptr[idx] + boffs[blockIdx.x];
        rowptr[idx] = v;
        cursor[idx] = v;
        if (idx == M - 1) rowptr[M] = v + counts[M - 1];
    }
}

// ---------------- scatter edges into CSR ----------------
__global__ __launch_bounds__(256) void scatter_k(const int* __restrict__ ci,
                                                 int* __restrict__ cursor,
                                                 int* __restrict__ edge_list, int L) {
    int l = blockIdx.x * 256 + threadIdx.x;
    if (l < L) {
        int pos = atomicAdd(&cursor[ci[l]], 1);
        edge_list[pos] = l;
    }
}

// ---------------- per-segment: softmax weights, h_hat, sum_f_c ----------------
__global__ __launch_bounds__(128) void segment_k(const int* __restrict__ rowptr,
                                                 const int* __restrict__ edge_list,
                                                 const int* __restrict__ chi,
                                                 const float* __restrict__ expe,
                                                 const __bf16* __restrict__ Wfx,
                                                 const __bf16* __restrict__ Ufh,
                                                 const __bf16* __restrict__ ch16,
                                                 const float* __restrict__ child_c,
                                                 __bf16* __restrict__ hhat,
                                                 float* __restrict__ sumfc, int M) {
    int m = blockIdx.x;
    int h = threadIdx.x;
    int start = rowptr[m], deg = rowptr[m + 1] - start;
    __shared__ float red[128];
    __shared__ int   sch[128];
    __shared__ float sa[128];

    float part = 0.f;
    for (int j = h; j < deg; j += 128) part += expe[edge_list[start + j]];
    red[h] = part;
    __syncthreads();
#pragma unroll
    for (int s = 64; s > 0; s >>= 1) {
        if (h < s) red[h] += red[h + s];
        __syncthreads();
    }
    float inv = 1.f / (red[0] + 1e-9f);
    __syncthreads();

    float wfx = (float)Wfx[(size_t)m * H + h];
    float acch = 0.f, accf = 0.f;

    for (int base = 0; base < deg; base += 128) {
        int n = deg - base; if (n > 128) n = 128;
        if (h < n) {
            int l = edge_list[start + base + h];
            sch[h] = chi[l];
            sa[h]  = expe[l] * inv;
        }
        __syncthreads();
        int j = 0;
        for (; j + 1 < n; j += 2) {
            int c0 = sch[j], c1 = sch[j + 1];
            size_t r0 = (size_t)c0 * H + h, r1 = (size_t)c1 * H + h;
            float h0 = (float)ch16[r0], h1 = (float)ch16[r1];
            float u0 = (float)Ufh[r0],  u1 = (float)Ufh[r1];
            float cc0 = child_c[r0],    cc1 = child_c[r1];
            acch += sa[j] * h0 + sa[j + 1] * h1;
            accf += fsigm(wfx + u0) * cc0 + fsigm(wfx + u1) * cc1;
        }
        if (j < n) {
            int c0 = sch[j];
            size_t r0 = (size_t)c0 * H + h;
            acch += sa[j] * (float)ch16[r0];
            accf += fsigm(wfx + (float)Ufh[r0]) * child_c[r0];
        }
        __syncthreads();
    }
    hhat[(size_t)m * H + h] = (__bf16)acch;
    sumfc[(size_t)m * H + h] = accf;
}

// ---------------- epilogue: gates -> h, c (x4 vectorized) ----------------
__global__ __launch_bounds__(256) void final_k(const __bf16* __restrict__ Xi, const __bf16* __restrict__ Hi,
                                               const __bf16* __restrict__ Xc, const __bf16* __restrict__ Hc,
                                               const __bf16* __restrict__ Xo, const __bf16* __restrict__ Ho,
                                               const float* __restrict__ sumfc,
                                               float* __restrict__ out, int MH4, int MH) {
    int i = blockIdx.x * 256 + threadIdx.x;
    if (i >= MH4) return;
    v4bf xi = ((const v4bf*)Xi)[i], hi = ((const v4bf*)Hi)[i];
    v4bf xc = ((const v4bf*)Xc)[i], hc = ((const v4bf*)Hc)[i];
    v4bf xo = ((const v4bf*)Xo)[i], ho = ((const v4bf*)Ho)[i];
    v4f sf = ((const v4f*)sumfc)[i];
    v4f hout, cout;
#pragma unroll
    for (int k = 0; k < 4; ++k) {
        float ig = fsigm((float)xi[k] + (float)hi[k]);
        float ct = ftanh((float)xc[k] + (float)hc[k]);
        float og = fsigm((float)xo[k] + (float)ho[k]);
        float c = ig * ct + sf[k];
        cout[k] = c;
        hout[k] = og * ftanh(c);
    }
    ((v4f*)out)[i] = hout;
    ((v4f*)(out + MH))[i] = cout;
}

extern "C" void kernel_launch(void* const* d_in, const int* in_sizes, int n_in,
                              void* d_out, int out_size, void* d_ws, size_t ws_size,
                              hipStream_t stream) {
    const float* x_emb   = (const float*)d_in[0];
    const float* child_h = (const float*)d_in[1];
    const float* child_c = (const float*)d_in[2];
    const int*   ci      = (const int*)d_in[3];
    const int*   chi     = (const int*)d_in[4];
    const float* Wi_w = (const float*)d_in[5];
    const float* Ui_w = (const float*)d_in[6];
    const float* Wf_w = (const float*)d_in[7];
    const float* Uf_w = (const float*)d_in[8];
    const float* Wo_w = (const float*)d_in[9];
    const float* Uo_w = (const float*)d_in[10];
    const float* Wc_w = (const float*)d_in[11];
    const float* Uc_w = (const float*)d_in[12];
    const float* Wa_w = (const float*)d_in[13];
    const float* Ua_w = (const float*)d_in[14];
    const float* Wi_b = (const float*)d_in[15];
    const float* Wf_b = (const float*)d_in[16];
    const float* Wo_b = (const float*)d_in[17];
    const float* Wc_b = (const float*)d_in[18];
    const float* Wa_b = (const float*)d_in[19];
    const float* vw   = (const float*)d_in[20];

    const int M    = in_sizes[0] / H;
    const int L    = in_sizes[3];
    const int Mpad = (M + 63) & ~63;
    const int MH   = M * H;

    char* p = (char*)d_ws;
    auto alloc = [&](size_t bytes) {
        char* r = p;
        p += (bytes + 255) & ~(size_t)255;
        return (void*)r;
    };
    size_t bfbytes = (size_t)Mpad * H * sizeof(__bf16);
    __bf16* xe16   = (__bf16*)alloc(bfbytes);
    __bf16* ch16   = (__bf16*)alloc(bfbytes);
    __bf16* hhat16 = (__bf16*)alloc(bfbytes);
    __bf16* Ah16   = (__bf16*)alloc(bfbytes);
    __bf16* Bx16   = (__bf16*)alloc(bfbytes);
    __bf16* Wfx16  = (__bf16*)alloc(bfbytes);
    __bf16* Ufh16  = (__bf16*)alloc(bfbytes);
    __bf16* Xi16   = (__bf16*)alloc(bfbytes);
    __bf16* Xc16   = (__bf16*)alloc(bfbytes);
    __bf16* Xo16   = (__bf16*)alloc(bfbytes);
    float* sumfc     = (float*)alloc((size_t)MH * 4);
    float* expe      = (float*)alloc((size_t)L * 4);
    int*   edge_list = (int*)alloc((size_t)L * 4);
    int*   counts    = (int*)alloc((size_t)M * 4);
    int*   rowptr    = (int*)alloc((size_t)(M + 1) * 4);
    int*   cursor    = (int*)alloc((size_t)M * 4);
    int*   bsums     = (int*)alloc(1024 * 4);
    int*   boffs     = (int*)alloc(1024 * 4);
    __bf16* Hi16 = Ah16;
    __bf16* Hc16 = Bx16;
    __bf16* Ho16 = Wfx16;

    const int MH4 = MH / 4;
    convert_k<<<(MH4 + 255) / 256, 256, 0, stream>>>(x_emb, child_h, xe16, ch16, MH4, counts, M);

    MatBatch ba{};
    ba.m[0] = MatDesc{ch16, Wa_w, Wa_b, Ah16};
    ba.m[1] = MatDesc{xe16, Ua_w, nullptr, Bx16};
    ba.m[2] = MatDesc{xe16, Wf_w, Wf_b, Wfx16};
    ba.m[3] = MatDesc{ch16, Uf_w, nullptr, Ufh16};
    ba.m[4] = MatDesc{xe16, Wi_w, Wi_b, Xi16};
    ba.m[5] = MatDesc{xe16, Wc_w, Wc_b, Xc16};
    ba.m[6] = MatDesc{xe16, Wo_w, Wo_b, Xo16};
    dim3 gA(Mpad / 64, 7);
    gemm_batch<<<gA, 256, 0, stream>>>(ba, M);

    edge_e<<<(L + 15) / 16, 256, 0, stream>>>(Ah16, Bx16, ci, chi, vw, expe, counts, L);

    int nb = (M + 1023) / 1024;
    scan_local<<<nb, 1024, 0, stream>>>(counts, rowptr, bsums, M);
    scan_tops<<<1, 1024, 0, stream>>>(bsums, boffs, nb);
    scan_add<<<nb, 1024, 0, stream>>>(rowptr, cursor, boffs, counts, M);

    scatter_k<<<(L + 255) / 256, 256, 0, stream>>>(ci, cursor, edge_list, L);
    segment_k<<<M, 128, 0, stream>>>(rowptr, edge_list, chi, expe, Wfx16, Ufh16, ch16, child_c,
                                     hhat16, sumfc, M);

    MatBatch bb{};
    bb.m[0] = MatDesc{hhat16, Ui_w, nullptr, Hi16};
    bb.m[1] = MatDesc{hhat16, Uc_w, nullptr, Hc16};
    bb.m[2] = MatDesc{hhat16, Uo_w, nullptr, Ho16};
    dim3 gB(Mpad / 64, 3);
    gemm_batch<<<gB, 256, 0, stream>>>(bb, M);

    final_k<<<(MH4 + 255) / 256, 256, 0, stream>>>(Xi16, Hi16, Xc16, Hc16, Xo16, Ho16, sumfc,
                                                   (float*)d_out, MH4, MH);
}

// Round 3
// 402.270 us; speedup vs baseline: 1.5520x; 1.0817x over previous
//
#include <hip/hip_runtime.h>
#include <cstdint>
#include <cstddef>

#define H 128
#define PSTRIDE 384   // packed row: [ch bf16 x128 | cc bf16 x128 | Ufh bf16 x128]

typedef __bf16 v8bf __attribute__((ext_vector_type(8)));
typedef __bf16 v4bf __attribute__((ext_vector_type(4)));
typedef float  v4f  __attribute__((ext_vector_type(4)));

__device__ __forceinline__ float ftanh(float x) {
    return 1.f - 2.f / (1.f + __expf(2.f * x));
}
__device__ __forceinline__ float fsigm(float x) {
    return 1.f / (1.f + __expf(-x));
}

struct MatDesc {
    const __bf16* A;    // bf16 A, row-major with stride lda
    int           lda;
    const __bf16* Wb;   // [128,128] bf16, row-major [n][k]
    const float*  bias; // [128] or nullptr
    __bf16*       C;    // bf16 out, stride ldc
    int           ldc;
};
struct MatBatch { MatDesc m[7]; };
struct WPtrs { const float* w[10]; };

// ---------------- weights fp32 -> bf16, all 10 mats ----------------
__global__ __launch_bounds__(256) void wconv(WPtrs wp, __bf16* __restrict__ Wb) {
    int i = blockIdx.x * 256 + threadIdx.x;   // v4 chunks; total 10*4096
    if (i >= 10 * 4096) return;
    int mat = i >> 12;
    int off = (i & 4095) << 2;
    v4f a = *(const v4f*)(wp.w[mat] + off);
    v4bf b;
#pragma unroll
    for (int k = 0; k < 4; ++k) b[k] = (__bf16)a[k];
    *(v4bf*)(Wb + mat * 16384 + off) = b;
}

// ---------------- convert: xe16, packed P rows (ch, cc), zero counts ----------------
__global__ __launch_bounds__(256) void convert_k(const float* __restrict__ x,
                                                 const float* __restrict__ chh,
                                                 const float* __restrict__ chc,
                                                 __bf16* __restrict__ xe,
                                                 __bf16* __restrict__ P,
                                                 int MH4, int* __restrict__ counts, int M) {
    int i = blockIdx.x * 256 + threadIdx.x;
    if (i < MH4) {
        v4f a = ((const v4f*)x)[i];
        v4f b = ((const v4f*)chh)[i];
        v4f c = ((const v4f*)chc)[i];
        v4bf ab, bb, cb;
#pragma unroll
        for (int k = 0; k < 4; ++k) {
            ab[k] = (__bf16)a[k]; bb[k] = (__bf16)b[k]; cb[k] = (__bf16)c[k];
        }
        ((v4bf*)xe)[i] = ab;
        int m = i >> 5;            // 32 v4-chunks per 128-row
        int q = (i & 31) << 2;
        __bf16* prow = P + (size_t)m * PSTRIDE + q;
        *(v4bf*)prow = bb;
        *(v4bf*)(prow + H) = cb;
    }
    if (i < M) counts[i] = 0;
}

// ---------------- batched GEMM: C = A @ W^T (+bias), bf16 MFMA ----------------
__global__ __launch_bounds__(256) void gemm_batch(MatBatch batch, int M) {
    const MatDesc d = batch.m[blockIdx.y];
    __shared__ __bf16 wlds[H][H + 8];

    // stage bf16 weight: 2048 v8 chunks, vectorized 16B copies
    for (int t = threadIdx.x; t < 2048; t += 256) {
        int n = t >> 4;
        int k = (t & 15) << 3;
        *(v8bf*)&wlds[n][k] = *(const v8bf*)(d.Wb + n * H + k);
    }
    __syncthreads();

    const int wave = threadIdx.x >> 6;
    const int lane = threadIdx.x & 63;
    const int quad = lane >> 4;
    const int l16  = lane & 15;
    const int r0   = blockIdx.x * 64 + wave * 16;

    v4f acc[8];
#pragma unroll
    for (int nt = 0; nt < 8; ++nt) acc[nt] = (v4f){0.f, 0.f, 0.f, 0.f};

    const __bf16* arow = d.A + (size_t)(r0 + l16) * d.lda + quad * 8;
#pragma unroll
    for (int k0 = 0; k0 < H; k0 += 32) {
        v8bf a = *(const v8bf*)(arow + k0);
#pragma unroll
        for (int nt = 0; nt < 8; ++nt) {
            v8bf b = *(const v8bf*)(&wlds[nt * 16 + l16][k0 + quad * 8]);
            acc[nt] = __builtin_amdgcn_mfma_f32_16x16x32_bf16(a, b, acc[nt], 0, 0, 0);
        }
    }

#pragma unroll
    for (int nt = 0; nt < 8; ++nt) {
        int n = nt * 16 + l16;
        float bia = d.bias ? d.bias[n] : 0.f;
#pragma unroll
        for (int r = 0; r < 4; ++r) {
            int m = r0 + quad * 4 + r;
            if (m < M) d.C[(size_t)m * d.ldc + n] = (__bf16)(acc[nt][r] + bia);
        }
    }
}

// ---------------- edge pass: 16 lanes/edge, 8 feats/lane; fast tanh; histogram ----------------
__global__ __launch_bounds__(256) void edge_e(const __bf16* __restrict__ Ah,
                                              const __bf16* __restrict__ Bx,
                                              const int* __restrict__ ci,
                                              const int* __restrict__ chi,
                                              const float* __restrict__ vw,
                                              float* __restrict__ expe,
                                              int* __restrict__ counts, int L) {
    int tid = threadIdx.x;
    int sub = tid & 15;
    int l = blockIdx.x * 16 + (tid >> 4);
    if (l >= L) return;
    int c = ci[l], ch = chi[l];
    v8bf a = *(const v8bf*)(Ah + (size_t)ch * H + sub * 8);
    v8bf b = *(const v8bf*)(Bx + (size_t)c * H + sub * 8);
    v4f v0 = *(const v4f*)(vw + sub * 8);
    v4f v1 = *(const v4f*)(vw + sub * 8 + 4);
    float s = 0.f;
#pragma unroll
    for (int k = 0; k < 8; ++k) {
        float x = (float)a[k] + (float)b[k];
        float vv = (k < 4) ? v0[k] : v1[k - 4];
        s += ftanh(x) * vv;
    }
    s += __shfl_xor(s, 1);
    s += __shfl_xor(s, 2);
    s += __shfl_xor(s, 4);
    s += __shfl_xor(s, 8);
    if (sub == 0) {
        expe[l] = __expf(s);
        atomicAdd(&counts[c], 1);
    }
}

// ---------------- 3-kernel parallel scan ----------------
__global__ __launch_bounds__(1024) void scan_local(const int* __restrict__ counts,
                                                   int* __restrict__ excl,
                                                   int* __restrict__ bsums, int M) {
    __shared__ int s[1024];
    int tid = threadIdx.x;
    int idx = blockIdx.x * 1024 + tid;
    int v = (idx < M) ? counts[idx] : 0;
    s[tid] = v;
    __syncthreads();
    for (int off = 1; off < 1024; off <<= 1) {
        int t = (tid >= off) ? s[tid - off] : 0;
        __syncthreads();
        s[tid] += t;
        __syncthreads();
    }
    if (idx < M) excl[idx] = s[tid] - v;
    if (tid == 1023) bsums[blockIdx.x] = s[1023];
}

__global__ __launch_bounds__(1024) void scan_tops(const int* __restrict__ bsums,
                                                  int* __restrict__ boffs, int nb) {
    __shared__ int s[1024];
    int tid = threadIdx.x;
    int v = (tid < nb) ? bsums[tid] : 0;
    s[tid] = v;
    __syncthreads();
    for (int off = 1; off < 1024; off <<= 1) {
        int t = (tid >= off) ? s[tid - off] : 0;
        __syncthreads();
        s[tid] += t;
        __syncthreads();
    }
    if (tid < nb) boffs[tid] = s[tid] - v;
}

__global__ __launch_bounds__(1024) void scan_add(int* __restrict__ rowptr,
                                                 int* __restrict__ cursor,
                                                 const int* __restrict__ boffs,
                                                 const int* __restrict__ counts, int M) {
    int idx = blockIdx.x * 1024 + threadIdx.x;
    if (idx < M) {
        int v = rowptr[idx] + boffs[blockIdx.x];
        rowptr[idx] = v;
        cursor[idx] = v;
        if (idx == M - 1) rowptr[M] = v + counts[M - 1];
    }
}

// ---------------- scatter edges into CSR ----------------
__global__ __launch_bounds__(256) void scatter_k(const int* __restrict__ ci,
                                                 int* __restrict__ cursor,
                                                 int* __restrict__ edge_list, int L) {
    int l = blockIdx.x * 256 + threadIdx.x;
    if (l < L) {
        int pos = atomicAdd(&cursor[ci[l]], 1);
        edge_list[pos] = l;
    }
}

// ---------------- per-segment: 32 lanes/segment, 4 feats/lane, b64 gathers ----------------
__global__ __launch_bounds__(128) void segment_k(const int* __restrict__ rowptr,
                                                 const int* __restrict__ edge_list,
                                                 const int* __restrict__ chi,
                                                 const float* __restrict__ expe,
                                                 const __bf16* __restrict__ Wfx,
                                                 const __bf16* __restrict__ P,
                                                 __bf16* __restrict__ hhat,
                                                 float* __restrict__ sumfc, int M) {
    int g    = threadIdx.x >> 5;
    int lane = threadIdx.x & 31;
    int m = blockIdx.x * 4 + g;
    if (m >= M) return;
    int start = rowptr[m], deg = rowptr[m + 1] - start;

    // segment softmax denominator (shuffle-only, stays within 32-lane group)
    float part = 0.f;
    for (int j = lane; j < deg; j += 32) part += expe[edge_list[start + j]];
    part += __shfl_xor(part, 1);
    part += __shfl_xor(part, 2);
    part += __shfl_xor(part, 4);
    part += __shfl_xor(part, 8);
    part += __shfl_xor(part, 16);
    float inv = 1.f / (part + 1e-9f);

    int h = lane << 2;
    v4bf wf4 = *(const v4bf*)(Wfx + (size_t)m * H + h);
    float wfx[4];
#pragma unroll
    for (int k = 0; k < 4; ++k) wfx[k] = (float)wf4[k];

    float acch[4] = {0.f, 0.f, 0.f, 0.f};
    float accf[4] = {0.f, 0.f, 0.f, 0.f};

    int j = 0;
    for (; j + 1 < deg; j += 2) {
        int l0 = edge_list[start + j], l1 = edge_list[start + j + 1];
        int c0 = chi[l0], c1 = chi[l1];
        float a0 = expe[l0] * inv, a1 = expe[l1] * inv;
        const __bf16* p0 = P + c0 * PSTRIDE + h;
        const __bf16* p1 = P + c1 * PSTRIDE + h;
        v4bf h0 = *(const v4bf*)p0;
        v4bf c4_0 = *(const v4bf*)(p0 + H);
        v4bf u0 = *(const v4bf*)(p0 + 2 * H);
        v4bf h1 = *(const v4bf*)p1;
        v4bf c4_1 = *(const v4bf*)(p1 + H);
        v4bf u1 = *(const v4bf*)(p1 + 2 * H);
#pragma unroll
        for (int k = 0; k < 4; ++k) {
            acch[k] += a0 * (float)h0[k] + a1 * (float)h1[k];
            accf[k] += fsigm(wfx[k] + (float)u0[k]) * (float)c4_0[k]
                     + fsigm(wfx[k] + (float)u1[k]) * (float)c4_1[k];
        }
    }
    if (j < deg) {
        int l0 = edge_list[start + j];
        int c0 = chi[l0];
        float a0 = expe[l0] * inv;
        const __bf16* p0 = P + c0 * PSTRIDE + h;
        v4bf h0 = *(const v4bf*)p0;
        v4bf c4_0 = *(const v4bf*)(p0 + H);
        v4bf u0 = *(const v4bf*)(p0 + 2 * H);
#pragma unroll
        for (int k = 0; k < 4; ++k) {
            acch[k] += a0 * (float)h0[k];
            accf[k] += fsigm(wfx[k] + (float)u0[k]) * (float)c4_0[k];
        }
    }

    v4bf hb;
    v4f sf;
#pragma unroll
    for (int k = 0; k < 4; ++k) { hb[k] = (__bf16)acch[k]; sf[k] = accf[k]; }
    *(v4bf*)(hhat + (size_t)m * H + h) = hb;
    *(v4f*)(sumfc + (size_t)m * H + h) = sf;
}

// ---------------- epilogue: gates -> h, c (x4 vectorized) ----------------
__global__ __launch_bounds__(256) void final_k(const __bf16* __restrict__ Xi, const __bf16* __restrict__ Hi,
                                               const __bf16* __restrict__ Xc, const __bf16* __restrict__ Hc,
                                               const __bf16* __restrict__ Xo, const __bf16* __restrict__ Ho,
                                               const float* __restrict__ sumfc,
                                               float* __restrict__ out, int MH4, int MH) {
    int i = blockIdx.x * 256 + threadIdx.x;
    if (i >= MH4) return;
    v4bf xi = ((const v4bf*)Xi)[i], hi = ((const v4bf*)Hi)[i];
    v4bf xc = ((const v4bf*)Xc)[i], hc = ((const v4bf*)Hc)[i];
    v4bf xo = ((const v4bf*)Xo)[i], ho = ((const v4bf*)Ho)[i];
    v4f sf = ((const v4f*)sumfc)[i];
    v4f hout, cout;
#pragma unroll
    for (int k = 0; k < 4; ++k) {
        float ig = fsigm((float)xi[k] + (float)hi[k]);
        float ct = ftanh((float)xc[k] + (float)hc[k]);
        float og = fsigm((float)xo[k] + (float)ho[k]);
        float c = ig * ct + sf[k];
        cout[k] = c;
        hout[k] = og * ftanh(c);
    }
    ((v4f*)out)[i] = hout;
    ((v4f*)(out + MH))[i] = cout;
}

extern "C" void kernel_launch(void* const* d_in, const int* in_sizes, int n_in,
                              void* d_out, int out_size, void* d_ws, size_t ws_size,
                              hipStream_t stream) {
    const float* x_emb   = (const float*)d_in[0];
    const float* child_h = (const float*)d_in[1];
    const float* child_c = (const float*)d_in[2];
    const int*   ci      = (const int*)d_in[3];
    const int*   chi     = (const int*)d_in[4];
    const float* Wi_b = (const float*)d_in[15];
    const float* Wf_b = (const float*)d_in[16];
    const float* Wo_b = (const float*)d_in[17];
    const float* Wc_b = (const float*)d_in[18];
    const float* Wa_b = (const float*)d_in[19];
    const float* vw   = (const float*)d_in[20];

    const int M    = in_sizes[0] / H;
    const int L    = in_sizes[3];
    const int Mpad = (M + 63) & ~63;
    const int MH   = M * H;

    char* p = (char*)d_ws;
    auto alloc = [&](size_t bytes) {
        char* r = p;
        p += (bytes + 255) & ~(size_t)255;
        return (void*)r;
    };
    size_t bfbytes = (size_t)Mpad * H * sizeof(__bf16);
    __bf16* xe16   = (__bf16*)alloc(bfbytes);
    __bf16* P      = (__bf16*)alloc((size_t)Mpad * PSTRIDE * sizeof(__bf16));
    __bf16* hhat16 = (__bf16*)alloc(bfbytes);
    __bf16* Ah16   = (__bf16*)alloc(bfbytes);
    __bf16* Bx16   = (__bf16*)alloc(bfbytes);
    __bf16* Wfx16  = (__bf16*)alloc(bfbytes);
    __bf16* Xi16   = (__bf16*)alloc(bfbytes);
    __bf16* Xc16   = (__bf16*)alloc(bfbytes);
    __bf16* Xo16   = (__bf16*)alloc(bfbytes);
    __bf16* Wb     = (__bf16*)alloc(10 * 16384 * sizeof(__bf16));
    float* sumfc     = (float*)alloc((size_t)MH * 4);
    float* expe      = (float*)alloc((size_t)L * 4);
    int*   edge_list = (int*)alloc((size_t)L * 4);
    int*   counts    = (int*)alloc((size_t)M * 4);
    int*   rowptr    = (int*)alloc((size_t)(M + 1) * 4);
    int*   cursor    = (int*)alloc((size_t)M * 4);
    int*   bsums     = (int*)alloc(1024 * 4);
    int*   boffs     = (int*)alloc(1024 * 4);
    __bf16* Hi16 = Ah16;
    __bf16* Hc16 = Bx16;
    __bf16* Ho16 = Wfx16;

    // weight order: Wi Ui Wf Uf Wo Uo Wc Uc Wa Ua (d_in[5..14])
    WPtrs wp;
    for (int k = 0; k < 10; ++k) wp.w[k] = (const float*)d_in[5 + k];
    wconv<<<(10 * 4096 + 255) / 256, 256, 0, stream>>>(wp, Wb);

    const int MH4 = MH / 4;
    convert_k<<<(MH4 + 255) / 256, 256, 0, stream>>>(x_emb, child_h, child_c, xe16, P, MH4, counts, M);

    const __bf16* Wi = Wb + 0 * 16384;
    const __bf16* Ui = Wb + 1 * 16384;
    const __bf16* Wf = Wb + 2 * 16384;
    const __bf16* Uf = Wb + 3 * 16384;
    const __bf16* Wo = Wb + 4 * 16384;
    const __bf16* Uo = Wb + 5 * 16384;
    const __bf16* Wc = Wb + 6 * 16384;
    const __bf16* Uc = Wb + 7 * 16384;
    const __bf16* Wa = Wb + 8 * 16384;
    const __bf16* Ua = Wb + 9 * 16384;

    MatBatch ba{};
    ba.m[0] = MatDesc{P,    PSTRIDE, Wa, Wa_b,    Ah16,    H};       // Ah = ch @ Wa^T + b
    ba.m[1] = MatDesc{xe16, H,       Ua, nullptr, Bx16,    H};       // Bx = x @ Ua^T
    ba.m[2] = MatDesc{xe16, H,       Wf, Wf_b,    Wfx16,   H};       // Wfx
    ba.m[3] = MatDesc{P,    PSTRIDE, Uf, nullptr, P + 2*H, PSTRIDE}; // Ufh -> packed section
    ba.m[4] = MatDesc{xe16, H,       Wi, Wi_b,    Xi16,    H};
    ba.m[5] = MatDesc{xe16, H,       Wc, Wc_b,    Xc16,    H};
    ba.m[6] = MatDesc{xe16, H,       Wo, Wo_b,    Xo16,    H};
    dim3 gA(Mpad / 64, 7);
    gemm_batch<<<gA, 256, 0, stream>>>(ba, M);

    edge_e<<<(L + 15) / 16, 256, 0, stream>>>(Ah16, Bx16, ci, chi, vw, expe, counts, L);

    int nb = (M + 1023) / 1024;
    scan_local<<<nb, 1024, 0, stream>>>(counts, rowptr, bsums, M);
    scan_tops<<<1, 1024, 0, stream>>>(bsums, boffs, nb);
    scan_add<<<nb, 1024, 0, stream>>>(rowptr, cursor, boffs, counts, M);

    scatter_k<<<(L + 255) / 256, 256, 0, stream>>>(ci, cursor, edge_list, L);
    segment_k<<<(M + 3) / 4, 128, 0, stream>>>(rowptr, edge_list, chi, expe, Wfx16, P,
                                               hhat16, sumfc, M);

    MatBatch bb{};
    bb.m[0] = MatDesc{hhat16, H, Ui, nullptr, Hi16, H};
    bb.m[1] = MatDesc{hhat16, H, Uc, nullptr, Hc16, H};
    bb.m[2] = MatDesc{hhat16, H, Uo, nullptr, Ho16, H};
    dim3 gB(Mpad / 64, 3);
    gemm_batch<<<gB, 256, 0, stream>>>(bb, M);

    final_k<<<(MH4 + 255) / 256, 256, 0, stream>>>(Xi16, Hi16, Xc16, Hc16, Xo16, Ho16, sumfc,
                                                   (float*)d_out, MH4, MH);
}

// Round 4
// 401.952 us; speedup vs baseline: 1.5533x; 1.0008x over previous
//
#include <hip/hip_runtime.h>
#include <cstdint>
#include <cstddef>

#define H 128
#define PSTRIDE 512   // packed row: [ch | cc | Ufh | Ah], all bf16 x128

typedef __bf16 v8bf __attribute__((ext_vector_type(8)));
typedef __bf16 v4bf __attribute__((ext_vector_type(4)));
typedef float  v4f  __attribute__((ext_vector_type(4)));

__device__ __forceinline__ float ftanh(float x) {
    return 1.f - 2.f / (1.f + __expf(2.f * x));
}
__device__ __forceinline__ float fsigm(float x) {
    return 1.f / (1.f + __expf(-x));
}

struct MatDesc {
    const __bf16* A;    // bf16 A, stride lda
    int           lda;
    const __bf16* Wb;   // [128,128] bf16 [n][k]
    const float*  bias; // [128] or nullptr
    __bf16*       C;    // bf16 out, stride ldc
    int           ldc;
};
struct MatBatch { MatDesc m[7]; };
struct WPtrs { const float* w[10]; };

// ---------------- prep: wconv (10 mats) + convert x/ch/cc + edge histogram ----------------
__global__ __launch_bounds__(256) void prep_k(WPtrs wp, __bf16* __restrict__ Wb,
                                              const float* __restrict__ x,
                                              const float* __restrict__ chh,
                                              const float* __restrict__ chc,
                                              __bf16* __restrict__ xe,
                                              __bf16* __restrict__ P,
                                              const int* __restrict__ ci,
                                              int* __restrict__ counts,
                                              int MH4, int L) {
    int tid = blockIdx.x * 256 + threadIdx.x;
    if (tid < 40960) {  // 10 * 4096 v4-chunks of weights
        int mat = tid >> 12;
        int off = (tid & 4095) << 2;
        v4f a = *(const v4f*)(wp.w[mat] + off);
        v4bf b;
#pragma unroll
        for (int k = 0; k < 4; ++k) b[k] = (__bf16)a[k];
        *(v4bf*)(Wb + mat * 16384 + off) = b;
        return;
    }
    int i = tid - 40960;
    if (i < MH4) {
        v4f a = ((const v4f*)x)[i];
        v4f b = ((const v4f*)chh)[i];
        v4f c = ((const v4f*)chc)[i];
        v4bf ab, bb, cb;
#pragma unroll
        for (int k = 0; k < 4; ++k) {
            ab[k] = (__bf16)a[k]; bb[k] = (__bf16)b[k]; cb[k] = (__bf16)c[k];
        }
        ((v4bf*)xe)[i] = ab;
        int m = i >> 5;
        int q = (i & 31) << 2;
        __bf16* prow = P + (size_t)m * PSTRIDE + q;
        *(v4bf*)prow = bb;
        *(v4bf*)(prow + H) = cb;
        return;
    }
    int l = i - MH4;
    if (l < L) atomicAdd(&counts[ci[l]], 1);
}

// ---------------- batched GEMM: 128 rows/block, 2 row-tiles/wave share B ds_reads ----------------
__global__ __launch_bounds__(256) void gemm_batch(MatBatch batch, int M) {
    const MatDesc d = batch.m[blockIdx.y];
    __shared__ __bf16 wlds[H][H + 8];

    for (int t = threadIdx.x; t < 2048; t += 256) {
        int n = t >> 4;
        int k = (t & 15) << 3;
        *(v8bf*)&wlds[n][k] = *(const v8bf*)(d.Wb + n * H + k);
    }
    __syncthreads();

    const int wave = threadIdx.x >> 6;
    const int lane = threadIdx.x & 63;
    const int quad = lane >> 4;
    const int l16  = lane & 15;
    const int r0   = blockIdx.x * 128 + wave * 32;

    v4f acc0[8], acc1[8];
#pragma unroll
    for (int nt = 0; nt < 8; ++nt) {
        acc0[nt] = (v4f){0.f, 0.f, 0.f, 0.f};
        acc1[nt] = (v4f){0.f, 0.f, 0.f, 0.f};
    }

    const __bf16* ar0 = d.A + (size_t)(r0 + l16) * d.lda + quad * 8;
    const __bf16* ar1 = d.A + (size_t)(r0 + 16 + l16) * d.lda + quad * 8;
#pragma unroll
    for (int k0 = 0; k0 < H; k0 += 32) {
        v8bf a0 = *(const v8bf*)(ar0 + k0);
        v8bf a1 = *(const v8bf*)(ar1 + k0);
#pragma unroll
        for (int nt = 0; nt < 8; ++nt) {
            v8bf b = *(const v8bf*)(&wlds[nt * 16 + l16][k0 + quad * 8]);
            acc0[nt] = __builtin_amdgcn_mfma_f32_16x16x32_bf16(a0, b, acc0[nt], 0, 0, 0);
            acc1[nt] = __builtin_amdgcn_mfma_f32_16x16x32_bf16(a1, b, acc1[nt], 0, 0, 0);
        }
    }

#pragma unroll
    for (int nt = 0; nt < 8; ++nt) {
        int n = nt * 16 + l16;
        float bia = d.bias ? d.bias[n] : 0.f;
#pragma unroll
        for (int r = 0; r < 4; ++r) {
            int m0 = r0 + quad * 4 + r;
            int m1 = m0 + 16;
            if (m0 < M) d.C[(size_t)m0 * d.ldc + n] = (__bf16)(acc0[nt][r] + bia);
            if (m1 < M) d.C[(size_t)m1 * d.ldc + n] = (__bf16)(acc1[nt][r] + bia);
        }
    }
}

// ---------------- scans ----------------
__global__ __launch_bounds__(1024) void scan_local(const int* __restrict__ counts,
                                                   int* __restrict__ excl,
                                                   int* __restrict__ bsums, int M) {
    __shared__ int s[1024];
    int tid = threadIdx.x;
    int idx = blockIdx.x * 1024 + tid;
    int v = (idx < M) ? counts[idx] : 0;
    s[tid] = v;
    __syncthreads();
    for (int off = 1; off < 1024; off <<= 1) {
        int t = (tid >= off) ? s[tid - off] : 0;
        __syncthreads();
        s[tid] += t;
        __syncthreads();
    }
    if (idx < M) excl[idx] = s[tid] - v;
    if (tid == 1023) bsums[blockIdx.x] = s[1023];
}

__global__ __launch_bounds__(1024) void scan_fused(int* __restrict__ rowptr,
                                                   int* __restrict__ cursor,
                                                   const int* __restrict__ bsums,
                                                   const int* __restrict__ counts,
                                                   int M, int nb) {
    __shared__ int s[1024];
    int t = threadIdx.x, b = blockIdx.x;
    int v = (t < nb) ? bsums[t] : 0;
    s[t] = v;
    __syncthreads();
    for (int off = 1; off < 1024; off <<= 1) {
        int tt = (t >= off) ? s[t - off] : 0;
        __syncthreads();
        s[t] += tt;
        __syncthreads();
    }
    int boff = (b == 0) ? 0 : s[b - 1];
    int idx = b * 1024 + t;
    if (idx < M) {
        int val = rowptr[idx] + boff;
        rowptr[idx] = val;
        cursor[idx] = val;
        if (idx == M - 1) rowptr[M] = val + counts[M - 1];
    }
}

// ---------------- scatter: CSR payload = child index ----------------
__global__ __launch_bounds__(256) void scatter_k(const int* __restrict__ ci,
                                                 const int* __restrict__ chi,
                                                 int* __restrict__ cursor,
                                                 int* __restrict__ payload, int L) {
    int l = blockIdx.x * 256 + threadIdx.x;
    if (l < L) {
        int pos = atomicAdd(&cursor[ci[l]], 1);
        payload[pos] = chi[l];
    }
}

// ---------------- fused attention + segment reduce: 32 lanes/segment ----------------
__global__ __launch_bounds__(128) void segment_fused(const int* __restrict__ rowptr,
                                                     const int* __restrict__ payload,
                                                     const float* __restrict__ vw,
                                                     const __bf16* __restrict__ Bx,
                                                     const __bf16* __restrict__ Wfx,
                                                     const __bf16* __restrict__ P,
                                                     __bf16* __restrict__ hhat,
                                                     float* __restrict__ sumfc, int M) {
    int wl   = threadIdx.x & 63;
    int half = wl & 32;
    int l32  = wl & 31;
    int m = blockIdx.x * 4 + (threadIdx.x >> 5);
    if (m >= M) return;
    int start = rowptr[m], deg = rowptr[m + 1] - start;
    int h = l32 << 2;

    v4bf bx4 = *(const v4bf*)(Bx + (size_t)m * H + h);
    v4bf wf4 = *(const v4bf*)(Wfx + (size_t)m * H + h);
    v4f  vv  = *(const v4f*)(vw + h);
    float bxf[4], wff[4];
#pragma unroll
    for (int k = 0; k < 4; ++k) { bxf[k] = (float)bx4[k]; wff[k] = (float)wf4[k]; }

    // batch payload loads (1 per lane per 32 edges)
    int pl0 = (l32 < deg) ? payload[start + l32] : 0;
    int pl1 = (32 + l32 < deg) ? payload[start + 32 + l32] : 0;

    int jcap = deg < 64 ? deg : 64;
    float e0 = 0.f, e1 = 0.f, denom = 0.f;

    // ---- pass 1: e_j = tanh(Ah[chi]+Bx[m]).v, keep exp(e_j) in regs ----
    for (int j = 0; j < jcap; ++j) {
        int cj = __shfl((j & 32) ? pl1 : pl0, half | (j & 31), 64);
        v4bf a4 = *(const v4bf*)(P + (size_t)cj * PSTRIDE + 3 * H + h);
        float s = 0.f;
#pragma unroll
        for (int k = 0; k < 4; ++k) s += ftanh((float)a4[k] + bxf[k]) * vv[k];
        s += __shfl_xor(s, 1);
        s += __shfl_xor(s, 2);
        s += __shfl_xor(s, 4);
        s += __shfl_xor(s, 8);
        s += __shfl_xor(s, 16);
        float ex = __expf(s);
        denom += ex;
        if (l32 == (j & 31)) { if (j & 32) e1 = ex; else e0 = ex; }
    }
    // rare overflow tail (deg > 64): accumulate denominator only
    for (int j = 64; j < deg; ++j) {
        int cj = payload[start + j];
        v4bf a4 = *(const v4bf*)(P + (size_t)cj * PSTRIDE + 3 * H + h);
        float s = 0.f;
#pragma unroll
        for (int k = 0; k < 4; ++k) s += ftanh((float)a4[k] + bxf[k]) * vv[k];
        s += __shfl_xor(s, 1);
        s += __shfl_xor(s, 2);
        s += __shfl_xor(s, 4);
        s += __shfl_xor(s, 8);
        s += __shfl_xor(s, 16);
        denom += __expf(s);
    }
    float inv = 1.f / (denom + 1e-9f);

    // ---- pass 2: gather [ch|cc|Ufh], apply attention + forget gates ----
    float acch[4] = {0.f, 0.f, 0.f, 0.f};
    float accf[4] = {0.f, 0.f, 0.f, 0.f};
#pragma unroll 2
    for (int j = 0; j < jcap; ++j) {
        int src = half | (j & 31);
        int   cj = __shfl((j & 32) ? pl1 : pl0, src, 64);
        float ex = __shfl((j & 32) ? e1 : e0, src, 64);
        float a = ex * inv;
        const __bf16* pb = P + (size_t)cj * PSTRIDE + h;
        v4bf h4 = *(const v4bf*)pb;
        v4bf c4 = *(const v4bf*)(pb + H);
        v4bf u4 = *(const v4bf*)(pb + 2 * H);
#pragma unroll
        for (int k = 0; k < 4; ++k) {
            acch[k] += a * (float)h4[k];
            accf[k] += fsigm(wff[k] + (float)u4[k]) * (float)c4[k];
        }
    }
    for (int j = 64; j < deg; ++j) {  // rare: recompute e
        int cj = payload[start + j];
        const __bf16* pb = P + (size_t)cj * PSTRIDE + h;
        v4bf a4 = *(const v4bf*)(pb + 3 * H);
        float s = 0.f;
#pragma unroll
        for (int k = 0; k < 4; ++k) s += ftanh((float)a4[k] + bxf[k]) * vv[k];
        s += __shfl_xor(s, 1);
        s += __shfl_xor(s, 2);
        s += __shfl_xor(s, 4);
        s += __shfl_xor(s, 8);
        s += __shfl_xor(s, 16);
        float a = __expf(s) * inv;
        v4bf h4 = *(const v4bf*)pb;
        v4bf c4 = *(const v4bf*)(pb + H);
        v4bf u4 = *(const v4bf*)(pb + 2 * H);
#pragma unroll
        for (int k = 0; k < 4; ++k) {
            acch[k] += a * (float)h4[k];
            accf[k] += fsigm(wff[k] + (float)u4[k]) * (float)c4[k];
        }
    }

    v4bf hb;
    v4f sf;
#pragma unroll
    for (int k = 0; k < 4; ++k) { hb[k] = (__bf16)acch[k]; sf[k] = accf[k]; }
    *(v4bf*)(hhat + (size_t)m * H + h) = hb;
    *(v4f*)(sumfc + (size_t)m * H + h) = sf;
}

// ---------------- epilogue ----------------
__global__ __launch_bounds__(256) void final_k(const __bf16* __restrict__ Xi, const __bf16* __restrict__ Hi,
                                               const __bf16* __restrict__ Xc, const __bf16* __restrict__ Hc,
                                               const __bf16* __restrict__ Xo, const __bf16* __restrict__ Ho,
                                               const float* __restrict__ sumfc,
                                               float* __restrict__ out, int MH4, int MH) {
    int i = blockIdx.x * 256 + threadIdx.x;
    if (i >= MH4) return;
    v4bf xi = ((const v4bf*)Xi)[i], hi = ((const v4bf*)Hi)[i];
    v4bf xc = ((const v4bf*)Xc)[i], hc = ((const v4bf*)Hc)[i];
    v4bf xo = ((const v4bf*)Xo)[i], ho = ((const v4bf*)Ho)[i];
    v4f sf = ((const v4f*)sumfc)[i];
    v4f hout, cout;
#pragma unroll
    for (int k = 0; k < 4; ++k) {
        float ig = fsigm((float)xi[k] + (float)hi[k]);
        float ct = ftanh((float)xc[k] + (float)hc[k]);
        float og = fsigm((float)xo[k] + (float)ho[k]);
        float c = ig * ct + sf[k];
        cout[k] = c;
        hout[k] = og * ftanh(c);
    }
    ((v4f*)out)[i] = hout;
    ((v4f*)(out + MH))[i] = cout;
}

extern "C" void kernel_launch(void* const* d_in, const int* in_sizes, int n_in,
                              void* d_out, int out_size, void* d_ws, size_t ws_size,
                              hipStream_t stream) {
    const float* x_emb   = (const float*)d_in[0];
    const float* child_h = (const float*)d_in[1];
    const float* child_c = (const float*)d_in[2];
    const int*   ci      = (const int*)d_in[3];
    const int*   chi     = (const int*)d_in[4];
    const float* Wi_b = (const float*)d_in[15];
    const float* Wf_b = (const float*)d_in[16];
    const float* Wo_b = (const float*)d_in[17];
    const float* Wc_b = (const float*)d_in[18];
    const float* Wa_b = (const float*)d_in[19];
    const float* vw   = (const float*)d_in[20];

    const int M    = in_sizes[0] / H;
    const int L    = in_sizes[3];
    const int Mpad = (M + 127) & ~127;
    const int MH   = M * H;
    const int MH4  = MH / 4;

    char* p = (char*)d_ws;
    auto alloc = [&](size_t bytes) {
        char* r = p;
        p += (bytes + 255) & ~(size_t)255;
        return (void*)r;
    };
    size_t bfbytes = (size_t)Mpad * H * sizeof(__bf16);
    __bf16* xe16   = (__bf16*)alloc(bfbytes);
    __bf16* P      = (__bf16*)alloc((size_t)Mpad * PSTRIDE * sizeof(__bf16));
    __bf16* hhat16 = (__bf16*)alloc(bfbytes);
    __bf16* Bx16   = (__bf16*)alloc(bfbytes);
    __bf16* Wfx16  = (__bf16*)alloc(bfbytes);
    __bf16* Xi16   = (__bf16*)alloc(bfbytes);
    __bf16* Xc16   = (__bf16*)alloc(bfbytes);
    __bf16* Xo16   = (__bf16*)alloc(bfbytes);
    __bf16* Wb     = (__bf16*)alloc(10 * 16384 * sizeof(__bf16));
    float* sumfc   = (float*)alloc((size_t)MH * 4);
    int*   payload = (int*)alloc((size_t)L * 4);
    int*   counts  = (int*)alloc((size_t)M * 4);
    int*   rowptr  = (int*)alloc((size_t)(M + 1) * 4);
    int*   cursor  = (int*)alloc((size_t)M * 4);
    int*   bsums   = (int*)alloc(1024 * 4);
    // reuse after segment_fused: Bx -> Hi, Wfx -> Hc, P -> Ho (flat)
    __bf16* Hi16 = Bx16;
    __bf16* Hc16 = Wfx16;
    __bf16* Ho16 = P;

    hipMemsetAsync(counts, 0, (size_t)M * 4, stream);

    WPtrs wp;
    for (int k = 0; k < 10; ++k) wp.w[k] = (const float*)d_in[5 + k];
    int prep_items = 40960 + MH4 + L;
    prep_k<<<(prep_items + 255) / 256, 256, 0, stream>>>(wp, Wb, x_emb, child_h, child_c,
                                                         xe16, P, ci, counts, MH4, L);

    const __bf16* Wi = Wb + 0 * 16384;
    const __bf16* Ui = Wb + 1 * 16384;
    const __bf16* Wf = Wb + 2 * 16384;
    const __bf16* Uf = Wb + 3 * 16384;
    const __bf16* Wo = Wb + 4 * 16384;
    const __bf16* Uo = Wb + 5 * 16384;
    const __bf16* Wc = Wb + 6 * 16384;
    const __bf16* Uc = Wb + 7 * 16384;
    const __bf16* Wa = Wb + 8 * 16384;
    const __bf16* Ua = Wb + 9 * 16384;

    MatBatch ba{};
    ba.m[0] = MatDesc{P,    PSTRIDE, Wa, Wa_b,    P + 3 * H, PSTRIDE}; // Ah -> P sec3
    ba.m[1] = MatDesc{xe16, H,       Ua, nullptr, Bx16,      H};       // Bx
    ba.m[2] = MatDesc{xe16, H,       Wf, Wf_b,    Wfx16,     H};       // Wfx
    ba.m[3] = MatDesc{P,    PSTRIDE, Uf, nullptr, P + 2 * H, PSTRIDE}; // Ufh -> P sec2
    ba.m[4] = MatDesc{xe16, H,       Wi, Wi_b,    Xi16,      H};
    ba.m[5] = MatDesc{xe16, H,       Wc, Wc_b,    Xc16,      H};
    ba.m[6] = MatDesc{xe16, H,       Wo, Wo_b,    Xo16,      H};
    dim3 gA(Mpad / 128, 7);
    gemm_batch<<<gA, 256, 0, stream>>>(ba, M);

    int nb = (M + 1023) / 1024;
    scan_local<<<nb, 1024, 0, stream>>>(counts, rowptr, bsums, M);
    scan_fused<<<nb, 1024, 0, stream>>>(rowptr, cursor, bsums, counts, M, nb);

    scatter_k<<<(L + 255) / 256, 256, 0, stream>>>(ci, chi, cursor, payload, L);

    segment_fused<<<(M + 3) / 4, 128, 0, stream>>>(rowptr, payload, vw, Bx16, Wfx16, P,
                                                   hhat16, sumfc, M);

    MatBatch bb{};
    bb.m[0] = MatDesc{hhat16, H, Ui, nullptr, Hi16, H};
    bb.m[1] = MatDesc{hhat16, H, Uc, nullptr, Hc16, H};
    bb.m[2] = MatDesc{hhat16, H, Uo, nullptr, Ho16, H};
    dim3 gB(Mpad / 128, 3);
    gemm_batch<<<gB, 256, 0, stream>>>(bb, M);

    final_k<<<(MH4 + 255) / 256, 256, 0, stream>>>(Xi16, Hi16, Xc16, Hc16, Xo16, Ho16, sumfc,
                                                   (float*)d_out, MH4, MH);
}